// Round 10
// baseline (36.463 us; speedup 1.0000x reference)
//
#include <hip/hip_runtime.h>

// GMP: y[b,s] = sum_{l=0}^{9} C_l(b,s) * x[b,s-l], zero for s < 20.
// C_l = sum_{k=0}^{3} a[k, 9-l] |x[s-l]|^k
//     + sum_{m=0}^{9} sum_{k=1}^{4} b[k-1,l,m] |x[s-l-1-m]|^k
// All fp32. Input c unused by the reference.
//
// Round-10: round-9 structure (coefficients via inline-asm s_load on the
// scalar pipe; no LDS, no barrier) with the byte-offset bug fixed:
// b is (4,10,10) so the k-stride from b+10*l is 100 floats = 0x190 bytes
// (round 9 wrongly used 0x640). Rows: x8 at 0x0/0x190/0x320/0x4b0,
// x2 tails at 0x20/0x1b0/0x340/0x4d0. a k-stride 0x28 (was correct).

typedef float f32x8 __attribute__((ext_vector_type(8)));
typedef float f32x2 __attribute__((ext_vector_type(2)));

constexpr int Lp = 10;
constexpr int Mp = 10;
constexpr int Dp = Lp + Mp;        // 20
constexpr int BLK = 256;
constexpr int T = 2;               // samples per thread
constexpr int TILE = BLK * T;      // 512 samples per block
constexpr int S_FIXED = 16384;

// Load iteration-l coefficients on the scalar pipe.
// bl = b + 10*l -> row k at byte offset k*0x190 (k-stride L*M=100 floats),
//                  each row 10 floats = x8 + x2 tail at +0x20.
// al = a + (9-l) -> a[k][9-l] at byte offsets k*0x28 (k-stride 10 floats).
__device__ __forceinline__ void load_coef(
    const float* bl, const float* al,
    f32x8& b0, f32x8& b1, f32x8& b2, f32x8& b3,
    f32x2& c0, f32x2& c1, f32x2& c2, f32x2& c3,
    float& a0, float& a1, float& a2, float& a3)
{
    asm volatile(
        "s_load_dwordx8 %0, %12, 0x0\n\t"
        "s_load_dwordx2 %4, %12, 0x20\n\t"
        "s_load_dwordx8 %1, %12, 0x190\n\t"
        "s_load_dwordx2 %5, %12, 0x1b0\n\t"
        "s_load_dwordx8 %2, %12, 0x320\n\t"
        "s_load_dwordx2 %6, %12, 0x340\n\t"
        "s_load_dwordx8 %3, %12, 0x4b0\n\t"
        "s_load_dwordx2 %7, %12, 0x4d0\n\t"
        "s_load_dword %8, %13, 0x0\n\t"
        "s_load_dword %9, %13, 0x28\n\t"
        "s_load_dword %10, %13, 0x50\n\t"
        "s_load_dword %11, %13, 0x78\n\t"
        "s_waitcnt lgkmcnt(0)"
        : "=&s"(b0), "=&s"(b1), "=&s"(b2), "=&s"(b3),
          "=&s"(c0), "=&s"(c1), "=&s"(c2), "=&s"(c3),
          "=&s"(a0), "=&s"(a1), "=&s"(a2), "=&s"(a3)
        : "s"(bl), "s"(al));
}

__global__ __launch_bounds__(BLK) void gmp_kernel(
    const float* __restrict__ x,   // (B, S, 2)
    const float* __restrict__ a,   // (K, L)
    const float* __restrict__ b,   // (K, L, M)
    float* __restrict__ out,       // (B, S, 2)
    int S)
{
    const int t = threadIdx.x;
    const int blocksPerRow = S / TILE;     // 32
    const int brow = blockIdx.x / blocksPerRow;
    const int s0   = (blockIdx.x % blocksPerRow) * TILE;
    const int sA   = s0 + 2 * t;           // first of this thread's 2 samples

    const float* xrow = x + (size_t)brow * S * 2;
    const float4* __restrict__ xr4 = reinterpret_cast<const float4*>(xrow);
    const float2* __restrict__ xr2 = reinterpret_cast<const float2*>(xrow);

    // Window position w (0..20) <-> complex sample p = sA + w - 19.
    // sample j, delay l: a-part w = 19+j-l; b-part w = 18+j-l-m.
    float q1[21], q2[21], q3[21], q4[21];
    float rex[11], imx[11];                // re/im of w = r+10

#define GMP_QUAD(i, vx, vy)                                   \
    {                                                         \
        const float m2_ = (vx) * (vx) + (vy) * (vy);          \
        const float r_  = __builtin_amdgcn_sqrtf(m2_);        \
        q1[(i)] = r_;  q2[(i)] = m2_;                         \
        q3[(i)] = m2_ * r_;  q4[(i)] = m2_ * m2_;             \
    }

    // w in [0,9): p in [sA-19, sA-10), 9 clamped float2 loads
    {
        #pragma unroll
        for (int i = 0; i < 9; ++i) {
            int p = sA - 19 + i;
            if (p < 0) p = 0;              // garbage -> masked outputs only
            const float2 v = xr2[p];
            GMP_QUAD(i, v.x, v.y);
        }
    }
    // w in [9,21): p in [sA-10, sA+2), 6 aligned float4 loads (sA even)
    {
        const int i4base = (sA - 10) / 2;
        #pragma unroll
        for (int n = 0; n < 6; ++n) {
            int idx = i4base + n;
            if (idx < 0) idx = 0;          // garbage -> masked outputs only
            const float4 f = xr4[idx];
            const int w0 = 9 + 2 * n, w1 = 10 + 2 * n;
            GMP_QUAD(w0, f.x, f.y);
            GMP_QUAD(w1, f.z, f.w);
            if (w0 >= 10) { rex[w0 - 10] = f.x; imx[w0 - 10] = f.y; }
            rex[w1 - 10] = f.z; imx[w1 - 10] = f.w;
        }
    }
#undef GMP_QUAD

    float yr0 = 0.f, yi0 = 0.f, yr1 = 0.f, yi1 = 0.f;

    #pragma unroll
    for (int l = 0; l < Lp; ++l) {
        f32x8 b0, b1, b2, b3;              // b[k][l][0..7] for k=0..3
        f32x2 c0, c1, c2, c3;              // b[k][l][8..9]
        float a0, a1, a2, a3;              // a[k][9-l]
        load_coef(b + 10 * l, a + (9 - l),
                  b0, b1, b2, b3, c0, c1, c2, c3, a0, a1, a2, a3);

        const int wa0 = 19 - l, wa1 = 20 - l;
        float C0 = a0 + a1 * q1[wa0] + a2 * q2[wa0] + a3 * q3[wa0];
        float C1 = a0 + a1 * q1[wa1] + a2 * q2[wa1] + a3 * q3[wa1];
        #pragma unroll
        for (int m = 0; m < 8; ++m) {
            const int w0 = 18 - l - m, w1 = 19 - l - m;
            C0 += b0[m] * q1[w0] + b1[m] * q2[w0] + b2[m] * q3[w0] + b3[m] * q4[w0];
            C1 += b0[m] * q1[w1] + b1[m] * q2[w1] + b2[m] * q3[w1] + b3[m] * q4[w1];
        }
        #pragma unroll
        for (int m = 8; m < 10; ++m) {
            const int w0 = 18 - l - m, w1 = 19 - l - m;
            C0 += c0[m - 8] * q1[w0] + c1[m - 8] * q2[w0]
                + c2[m - 8] * q3[w0] + c3[m - 8] * q4[w0];
            C1 += c0[m - 8] * q1[w1] + c1[m - 8] * q2[w1]
                + c2[m - 8] * q3[w1] + c3[m - 8] * q4[w1];
        }
        const int r = 9 - l;               // rex index for j=0 (j=1 -> r+1)
        yr0 += C0 * rex[r];     yi0 += C0 * imx[r];
        yr1 += C1 * rex[r + 1]; yi1 += C1 * imx[r + 1];
    }

    // masked store: 2 consecutive float2 = 1 float4 store
    const bool k0 = (sA + 0) >= Dp, k1 = (sA + 1) >= Dp;
    const float4 o = make_float4(k0 ? yr0 : 0.f, k0 ? yi0 : 0.f,
                                 k1 ? yr1 : 0.f, k1 ? yi1 : 0.f);
    reinterpret_cast<float4*>(out)[((size_t)brow * S + sA) / 2] = o;
}

extern "C" void kernel_launch(void* const* d_in, const int* in_sizes, int n_in,
                              void* d_out, int out_size, void* d_ws, size_t ws_size,
                              hipStream_t stream) {
    const float* x = (const float*)d_in[0];
    const float* a = (const float*)d_in[1];
    const float* b = (const float*)d_in[2];
    // d_in[3] (c) is unused by the reference.
    float* out = (float*)d_out;

    const int S = S_FIXED;
    const int B = in_sizes[0] / (2 * S);
    const int nblocks = B * (S / TILE);

    gmp_kernel<<<dim3(nblocks), dim3(BLK), 0, stream>>>(x, a, b, out, S);
}

// Round 13
// 10.931 us; speedup vs baseline: 3.3356x; 3.3356x over previous
//
#include <hip/hip_runtime.h>

// GMP via MFMA: y[s] = sum_l (W[s-l,l] + a0[l]) * x[s-l], masked s<20.
// W[v,l] = sum_f Phi[v][f] * Theta[f][l]  (GEMM, K=64 padded)
//   Phi[v][4j+c] = q_{c+1}[v-j], j=0..10 valid    q_k = |x|^k
//   Theta[4*0+c][l] = a[c+1][9-l] (c<3), 0 for c=3
//   Theta[4(1+m)+c][l] = b[c][l][m], m=0..9
//   Theta rows f>=44 are ZERO (round-12 bug: f<48 let j=11 read b[..][10],
//   an out-of-range coefficient -> absmax 2840). f>=44 or l>=10 -> 0.
//   bias a0[l] = a[0][9-l] added in the combine epilogue.
// Per wave: 128 samples, 9 position-groups of 16, 2 MFMA each.
// Coefficients enter via ONE B-fragment pair per wave (2 ds_read_b128)
// instead of r6's 110 broadcast b128 reads -- the structural fix.

typedef short short8 __attribute__((ext_vector_type(8)));
typedef float f32x4 __attribute__((ext_vector_type(4)));

constexpr int S_FIXED = 16384;
constexpr int BLK = 256;          // 4 waves
constexpr int TILE = 512;         // samples per block (128 per wave)

__device__ __forceinline__ unsigned short bfc(float f) {
    union { float f; unsigned u; } v; v.f = f;
    const unsigned u = v.u;
    return (unsigned short)((u + 0x7FFFu + ((u >> 16) & 1u)) >> 16);
}

__device__ __forceinline__ short8 mk8(ushort4 lo, ushort4 hi) {
    union { ushort4 u[2]; short8 s; } x;
    x.u[0] = lo; x.u[1] = hi;
    return x.s;
}

__global__ __launch_bounds__(BLK) void gmp_mfma(
    const float* __restrict__ x,   // (B, S, 2)
    const float* __restrict__ a,   // (4, 10)
    const float* __restrict__ b,   // (4, 10, 10)
    float* __restrict__ out,       // (B, S, 2)
    int S)
{
    __shared__ alignas(16) unsigned short th[16][64];   // Theta[col=l][f] bf16
    __shared__ alignas(16) ushort4 qr[4][160];          // per-wave reversed quads
    __shared__ alignas(16) float wl[4][10][148];        // per-wave W[l][pos-idx]

    const int t = threadIdx.x;
    const int wid = t >> 6, lane = t & 63;
    const int m = lane & 15, h = lane >> 4;
    const int blocksPerRow = S / TILE;                  // 32
    const int brow = blockIdx.x / blocksPerRow;
    const int s0   = (blockIdx.x % blocksPerRow) * TILE;
    const int s0w  = s0 + 128 * wid;                    // this wave's samples
    const int vb   = s0w - 12;                          // position base

    // ---- Theta build (block-wide, 1024 entries) ----
    for (int idx = t; idx < 1024; idx += BLK) {
        const int col = idx >> 6, f = idx & 63;
        float v = 0.f;
        if (col < 10 && f < 44) {            // j <= 10 only (FIX vs round 12)
            const int j = f >> 2, c = f & 3;
            if (j == 0) { if (c < 3) v = a[(c + 1) * 10 + (9 - col)]; }
            else v = b[c * 100 + col * 10 + (j - 1)];
        }
        th[col][f] = bfc(v);
    }

    // ---- Q build: reversed quad table, qr[wid][i] = quads(vb + 143 - i) ----
    // entries with position out of range are zero / only hit zero Theta rows.
    const float2* __restrict__ xr2 =
        reinterpret_cast<const float2*>(x) + (size_t)brow * S;
    for (int i = lane; i < 160; i += 64) {
        const int p = vb + 143 - i;
        float xre = 0.f, xim = 0.f;
        if (p >= 0 && p < S) { const float2 v = xr2[p]; xre = v.x; xim = v.y; }
        const float m2 = xre * xre + xim * xim;
        const float r  = __builtin_amdgcn_sqrtf(m2);
        ushort4 q;
        q.x = bfc(r); q.y = bfc(m2); q.z = bfc(m2 * r); q.w = bfc(m2 * m2);
        qr[wid][i] = q;
    }
    __syncthreads();   // th visible to all waves (qr is wave-private)

    // ---- B fragments (coefficients; once per wave) ----
    const short8 bfr0 = *reinterpret_cast<const short8*>(&th[m][8 * h]);
    const short8 bfr1 = *reinterpret_cast<const short8*>(&th[m][8 * h + 32]);

    // ---- MFMA: 9 groups of 16 positions; W -> LDS ----
    #pragma unroll
    for (int g = 0; g < 9; ++g) {
        // A row m -> position p_m = vb + 16g + m; k-chunk h -> quads at
        // p_m-2h, p_m-2h-1 (frag0) and p_m-2h-8, p_m-2h-9 (frag1).
        const int i1 = 143 - 16 * g - m + 2 * h;
        const short8 af0 = mk8(qr[wid][i1],     qr[wid][i1 + 1]);
        const short8 af1 = mk8(qr[wid][i1 + 8], qr[wid][i1 + 9]);
        f32x4 acc = {0.f, 0.f, 0.f, 0.f};
        acc = __builtin_amdgcn_mfma_f32_16x16x32_bf16(af0, bfr0, acc, 0, 0, 0);
        acc = __builtin_amdgcn_mfma_f32_16x16x32_bf16(af1, bfr1, acc, 0, 0, 0);
        // D: col = lane&15 (= l), rows (lane>>4)*4 + r (= position offset)
        if (m < 10)
            *reinterpret_cast<f32x4*>(&wl[wid][m][16 * g + 4 * h]) = acc;
    }

    // ---- combine epilogue: 2 samples per lane ----
    const int sa0 = s0w + 2 * lane;
    const float4* __restrict__ xr4 =
        reinterpret_cast<const float4*>(x) + (size_t)brow * (S / 2);
    float xf[24];   // complex window [sa0-10, sa0+2)
    {
        const int base4 = (sa0 - 10) / 2;   // sa0 even -> exact
        #pragma unroll
        for (int n = 0; n < 6; ++n) {
            int idx = base4 + n;
            if (idx < 0) idx = 0;           // garbage -> masked s<20 only
            const float4 f4 = xr4[idx];
            xf[4 * n + 0] = f4.x; xf[4 * n + 1] = f4.y;
            xf[4 * n + 2] = f4.z; xf[4 * n + 3] = f4.w;
        }
    }
    float yr0 = 0.f, yi0 = 0.f, yr1 = 0.f, yi1 = 0.f;
    #pragma unroll
    for (int l = 0; l < 10; ++l) {
        const float bl = a[9 - l];                       // a[0][9-l]
        const float w0 = wl[wid][l][2 * lane + 12 - l] + bl;
        const float w1 = wl[wid][l][2 * lane + 13 - l] + bl;
        const int wp = 10 - l;                           // window pos, jj=0
        yr0 += w0 * xf[2 * wp];     yi0 += w0 * xf[2 * wp + 1];
        yr1 += w1 * xf[2 * wp + 2]; yi1 += w1 * xf[2 * wp + 3];
    }
    const bool k0 = sa0 >= 20, k1 = (sa0 + 1) >= 20;
    const float4 o = make_float4(k0 ? yr0 : 0.f, k0 ? yi0 : 0.f,
                                 k1 ? yr1 : 0.f, k1 ? yi1 : 0.f);
    reinterpret_cast<float4*>(out)[((size_t)brow * S + sa0) / 2] = o;
}

extern "C" void kernel_launch(void* const* d_in, const int* in_sizes, int n_in,
                              void* d_out, int out_size, void* d_ws, size_t ws_size,
                              hipStream_t stream) {
    const float* x = (const float*)d_in[0];
    const float* a = (const float*)d_in[1];
    const float* b = (const float*)d_in[2];
    // d_in[3] (c) is unused by the reference.
    float* out = (float*)d_out;

    const int S = S_FIXED;
    const int B = in_sizes[0] / (2 * S);
    const int nblocks = B * (S / TILE);

    gmp_mfma<<<dim3(nblocks), dim3(BLK), 0, stream>>>(x, a, b, out, S);
}